// Round 3
// baseline (174.100 us; speedup 1.0000x reference)
//
#include <hip/hip_runtime.h>
#include <hip/hip_bf16.h>

#define BB 4
#define CC 128
#define TWOC 256
#define NN 4096
#define KK 16
#define COUT 256
#define NPB 16                 // nodes per k1 block
#define BNK (BB*NN*KK)
#define K1GRID ((BB*NN)/NPB)   // 1024

typedef __attribute__((ext_vector_type(8))) short short8;
typedef __attribute__((ext_vector_type(4))) float f32x4;

__device__ __forceinline__ short f2bs(float f) {
  union { __hip_bfloat16 h; short s; } u;
  u.h = __float2bfloat16(f);
  return u.s;
}
__device__ __forceinline__ float bs2f(unsigned short s) {
  union { unsigned int u; float f; } v;
  v.u = ((unsigned int)s) << 16;
  return v.f;
}

// K0: transpose x [B][C][N] f32 -> featbf [B][N][C] bf16
__global__ void __launch_bounds__(256) k0_transpose(const float* __restrict__ x,
                                                    unsigned short* __restrict__ featbf) {
  __shared__ float tile[64][129];
  int b = blockIdx.x >> 6;
  int n0 = (blockIdx.x & 63) << 6;
  int t = threadIdx.x;
#pragma unroll
  for (int i = 0; i < 32; ++i) {
    int flat = t + i * 256;
    int c = flat >> 6;
    int nl = flat & 63;
    tile[nl][c] = x[((size_t)(b * CC + c) * NN) + n0 + nl];
  }
  __syncthreads();
#pragma unroll
  for (int i = 0; i < 8; ++i) {
    int e = t + i * 256;
    int c4 = (e & 31) << 2;
    int nl = e >> 5;
    ushort4 u;
    u.x = (unsigned short)f2bs(tile[nl][c4 + 0]);
    u.y = (unsigned short)f2bs(tile[nl][c4 + 1]);
    u.z = (unsigned short)f2bs(tile[nl][c4 + 2]);
    u.w = (unsigned short)f2bs(tile[nl][c4 + 3]);
    *(ushort4*)(featbf + ((size_t)(b * NN + n0 + nl) * CC + c4)) = u;
  }
}

// K1: pipelined gather -> h[16][256] (double-buffered, XOR-swizzled LDS) -> MFMA
__global__ void __launch_bounds__(256, 2) k1_main(
    const unsigned short* __restrict__ featbf,
    const float* __restrict__ w, const float* __restrict__ bias,
    const int* __restrict__ eidx,
    float* __restrict__ nmax, float* __restrict__ nmin,
    float* __restrict__ gsum, float* __restrict__ gsq)
{
  __shared__ short hsh[2][16 * 256];   // 2 x 8 KB double buffer
  const int tid = threadIdx.x;
  const int wave = tid >> 6;
  const int lane = tid & 63;
  const int l15 = lane & 15;
  const int lhi = lane >> 4;
  const int colbase = wave * 64;

  short8 bfrag[8][4];
#pragma unroll
  for (int t = 0; t < 8; ++t)
#pragma unroll
    for (int ct = 0; ct < 4; ++ct) {
      int col = colbase + ct * 16 + l15;
      int k0 = t * 32 + lhi * 8;
      const float* wr = w + (size_t)col * TWOC + k0;
      short8 f;
#pragma unroll
      for (int j = 0; j < 8; ++j) f[j] = f2bs(wr[j]);
      bfrag[t][ct] = f;
    }
  float biasv[4];
#pragma unroll
  for (int ct = 0; ct < 4; ++ct) biasv[ct] = bias[colbase + ct * 16 + l15];

  float cs[4] = {0.f, 0.f, 0.f, 0.f};
  float cq[4] = {0.f, 0.f, 0.f, 0.f};

  const int r  = tid >> 4;
  const int c8 = (tid & 15) * 8;
  const int swz = (r & 7) << 4;

  const int g0 = blockIdx.x * NPB;
  const int b  = g0 >> 12;
  const int n0 = g0 & (NN - 1);
  const unsigned short* fb = featbf + (size_t)b * NN * CC;
  const int* e0 = eidx + ((b * NN + n0) * KK + r);   // edge_index[0] (x_j)
  const int* e1 = e0 + BNK;                          // edge_index[1] (x_i)

  auto stage = [&](char* hb, uint4 Fi, uint4 Fj) {
    *(uint4*)(hb + (((r * 256 + c8) * 2) ^ swz)) = Fi;
    uint4 d;
    unsigned int* pi = (unsigned int*)&Fi;
    unsigned int* pj = (unsigned int*)&Fj;
    unsigned int* pd = (unsigned int*)&d;
#pragma unroll
    for (int q = 0; q < 4; ++q) {
      float lo = bs2f((unsigned short)(pj[q] & 0xffff)) - bs2f((unsigned short)(pi[q] & 0xffff));
      float hi = bs2f((unsigned short)(pj[q] >> 16))    - bs2f((unsigned short)(pi[q] >> 16));
      pd[q] = ((unsigned int)(unsigned short)f2bs(lo)) |
              (((unsigned int)(unsigned short)f2bs(hi)) << 16);
    }
    *(uint4*)(hb + (((r * 256 + 128 + c8) * 2) ^ swz)) = d;
  };

  uint4 fi, fj;

  {
    int ij = e0[0], ii = e1[0];
    uint4 Fj = *(const uint4*)(fb + (size_t)ij * CC + c8);
    uint4 Fi = *(const uint4*)(fb + (size_t)ii * CC + c8);
    stage((char*)hsh[0], Fi, Fj);
    int ij1 = e0[KK], ii1 = e1[KK];
    fj = *(const uint4*)(fb + (size_t)ij1 * CC + c8);
    fi = *(const uint4*)(fb + (size_t)ii1 * CC + c8);
  }
  __syncthreads();

  const int aswz = (l15 & 7) << 4;

  for (int it = 0; it < NPB; ++it) {
    char* hb = (char*)hsh[it & 1];
    char* hn = (char*)hsh[(it & 1) ^ 1];

    int ij2 = 0, ii2 = 0;
    if (it + 2 < NPB) { ij2 = e0[(it + 2) * KK]; ii2 = e1[(it + 2) * KK]; }

    short8 a[8];
#pragma unroll
    for (int t = 0; t < 8; ++t)
      a[t] = *(short8*)(hb + (((l15 * 256 + t * 32 + lhi * 8) * 2) ^ aswz));

    f32x4 acc[4] = {};
#pragma unroll
    for (int ct = 0; ct < 4; ++ct)
#pragma unroll
      for (int t = 0; t < 8; ++t)
        acc[ct] = __builtin_amdgcn_mfma_f32_16x16x32_bf16(a[t], bfrag[t][ct], acc[ct], 0, 0, 0);

    if (it + 1 < NPB) {
      stage(hn, fi, fj);
      if (it + 2 < NPB) {
        fj = *(const uint4*)(fb + (size_t)ij2 * CC + c8);
        fi = *(const uint4*)(fb + (size_t)ii2 * CC + c8);
      }
    }

    const int g = g0 + it;
#pragma unroll
    for (int ct = 0; ct < 4; ++ct) {
      float vmax = -1e30f, vmin = 1e30f, vs = 0.f, vq = 0.f;
#pragma unroll
      for (int i = 0; i < 4; ++i) {
        float v = acc[ct][i] + biasv[ct];
        v = fmaxf(v, 0.f);
        vmax = fmaxf(vmax, v);
        vmin = fminf(vmin, v);
        vs += v;
        vq += v * v;
      }
      cs[ct] += vs;
      cq[ct] += vq;
      vmax = fmaxf(vmax, __shfl_xor(vmax, 16));
      vmax = fmaxf(vmax, __shfl_xor(vmax, 32));
      vmin = fminf(vmin, __shfl_xor(vmin, 16));
      vmin = fminf(vmin, __shfl_xor(vmin, 32));
      if (lane < 16) {
        int col = colbase + ct * 16 + l15;
        nmax[(size_t)g * COUT + col] = vmax;
        nmin[(size_t)g * COUT + col] = vmin;
      }
    }
    __syncthreads();
  }

#pragma unroll
  for (int ct = 0; ct < 4; ++ct) {
    float s = cs[ct], q = cq[ct];
    s += __shfl_xor(s, 16);  s += __shfl_xor(s, 32);
    q += __shfl_xor(q, 16);  q += __shfl_xor(q, 32);
    if (lane < 16) {
      int col = colbase + ct * 16 + l15;
      atomicAdd(&gsum[col], s);
      atomicAdd(&gsq[col], q);
    }
  }
}

// K2: fused BN-affine finalize + monotone max/min select + transposed output
__global__ void __launch_bounds__(256) k2_out(const float* __restrict__ nmax,
                                              const float* __restrict__ nmin,
                                              const float* __restrict__ gsum,
                                              const float* __restrict__ gsq,
                                              const float* __restrict__ gamma,
                                              const float* __restrict__ beta,
                                              float* __restrict__ out) {
  __shared__ float tile[COUT][33];
  int b = blockIdx.x >> 7;
  int n0 = (blockIdx.x & 127) << 5;
  int t = threadIdx.x;
  const float inv = 1.0f / (float)BNK;
  float mean = gsum[t] * inv;
  float var  = gsq[t] * inv - mean * mean;
  float sc = gamma[t] * rsqrtf(var + 1e-5f);
  float sh = beta[t] - mean * sc;
  const float* src = (sc >= 0.f) ? nmax : nmin;
#pragma unroll
  for (int rr = 0; rr < 32; ++rr) {
    size_t g = (size_t)(b * NN + n0 + rr) * COUT + t;
    tile[t][rr] = src[g] * sc + sh;
  }
  __syncthreads();
#pragma unroll
  for (int i = 0; i < 32; ++i) {
    int o = i * 8 + (t >> 5);
    int nl = t & 31;
    out[((size_t)(b * COUT + o) * NN) + n0 + nl] = tile[o][nl];
  }
}

extern "C" void kernel_launch(void* const* d_in, const int* in_sizes, int n_in,
                              void* d_out, int out_size, void* d_ws, size_t ws_size,
                              hipStream_t stream) {
  const float* x     = (const float*)d_in[0];
  const float* w     = (const float*)d_in[1];
  const float* bias  = (const float*)d_in[2];
  const float* gamma = (const float*)d_in[3];
  const float* beta  = (const float*)d_in[4];
  const int*   eidx  = (const int*)d_in[5];

  char* ws = (char*)d_ws;
  unsigned short* featbf = (unsigned short*)(ws);            //  4,194,304 B
  float* nmax   = (float*)(ws + 4194304);                    // 16,777,216 B
  float* nmin   = (float*)(ws + 20971520);                   // 16,777,216 B
  float* gsum   = (float*)(ws + 37748736);                   //      1,024 B
  float* gsq    = (float*)(ws + 37749760);                   //      1,024 B
  float* out = (float*)d_out;

  hipMemsetAsync(gsum, 0, 2048, stream);  // zeros gsum+gsq (adjacent)
  k0_transpose<<<256, 256, 0, stream>>>(x, featbf);
  k1_main<<<K1GRID, 256, 0, stream>>>(featbf, w, bias, eidx, nmax, nmin, gsum, gsq);
  k2_out<<<512, 256, 0, stream>>>(nmax, nmin, gsum, gsq, gamma, beta, out);
}

// Round 4
// 157.861 us; speedup vs baseline: 1.1029x; 1.1029x over previous
//
#include <hip/hip_runtime.h>
#include <hip/hip_bf16.h>

#define BB 4
#define CC 128
#define TWOC 256
#define NN 4096
#define KK 16
#define COUT 256
#define NPB 32                 // nodes per k1 block (16 pairs)
#define BNK (BB*NN*KK)
#define K1GRID ((BB*NN)/NPB)   // 512
#define NPAIR (NPB/2)          // 16

typedef __attribute__((ext_vector_type(8))) short short8;
typedef __attribute__((ext_vector_type(4))) float f32x4;

__device__ __forceinline__ short f2bs(float f) {
  union { __hip_bfloat16 h; short s; } u;
  u.h = __float2bfloat16(f);
  return u.s;
}
__device__ __forceinline__ float bs2f(unsigned short s) {
  union { unsigned int u; float f; } v;
  v.u = ((unsigned int)s) << 16;
  return v.f;
}

// K0: transpose x [B][C][N] f32 -> featbf [B][N][C] bf16; block 0 zeroes stats
__global__ void __launch_bounds__(256) k0_transpose(const float* __restrict__ x,
                                                    unsigned short* __restrict__ featbf,
                                                    float* __restrict__ gsum,
                                                    float* __restrict__ gsq) {
  __shared__ float tile[64][129];
  int b = blockIdx.x >> 6;
  int n0 = (blockIdx.x & 63) << 6;
  int t = threadIdx.x;
  if (blockIdx.x == 0) { gsum[t] = 0.f; gsq[t] = 0.f; }
#pragma unroll
  for (int i = 0; i < 32; ++i) {
    int flat = t + i * 256;
    int c = flat >> 6;
    int nl = flat & 63;
    tile[nl][c] = x[((size_t)(b * CC + c) * NN) + n0 + nl];
  }
  __syncthreads();
#pragma unroll
  for (int i = 0; i < 8; ++i) {
    int e = t + i * 256;
    int c4 = (e & 31) << 2;
    int nl = e >> 5;
    ushort4 u;
    u.x = (unsigned short)f2bs(tile[nl][c4 + 0]);
    u.y = (unsigned short)f2bs(tile[nl][c4 + 1]);
    u.z = (unsigned short)f2bs(tile[nl][c4 + 2]);
    u.w = (unsigned short)f2bs(tile[nl][c4 + 3]);
    *(ushort4*)(featbf + ((size_t)(b * NN + n0 + nl) * CC + c4)) = u;
  }
}

// K1: 512 threads, 8 waves x 32 cols; 2 nodes (32 rows) per iteration;
//     double-buffered swizzled LDS; pipelined gathers; bf16 minmax out.
__global__ void __launch_bounds__(512, 4) k1_main(
    const unsigned short* __restrict__ featbf,
    const float* __restrict__ w, const float* __restrict__ bias,
    const int* __restrict__ eidx,
    unsigned short* __restrict__ nmaxh, unsigned short* __restrict__ nminh,
    float* __restrict__ gsum, float* __restrict__ gsq)
{
  __shared__ short hsh[2][32 * 256];   // 2 x 16 KB
  const int tid = threadIdx.x;
  const int wv   = tid >> 6;        // 0..7
  const int lane = tid & 63;
  const int l15  = lane & 15;
  const int lhi  = lane >> 4;
  const int colbase = wv * 32;

  // B fragments: lane holds k = t*32 + lhi*8 + j, col = colbase + ct*16 + l15
  short8 bfrag[8][2];
#pragma unroll
  for (int t = 0; t < 8; ++t)
#pragma unroll
    for (int ct = 0; ct < 2; ++ct) {
      int col = colbase + ct * 16 + l15;
      int k0 = t * 32 + lhi * 8;
      const float* wr = w + (size_t)col * TWOC + k0;
      short8 f;
#pragma unroll
      for (int j = 0; j < 8; ++j) f[j] = f2bs(wr[j]);
      bfrag[t][ct] = f;
    }
  float biasv[2];
#pragma unroll
  for (int ct = 0; ct < 2; ++ct) biasv[ct] = bias[colbase + ct * 16 + l15];

  float cs[2] = {0.f, 0.f};
  float cq[2] = {0.f, 0.f};

  const int rr  = tid >> 4;         // staging row 0..31 (node pair: 2 x 16 rows)
  const int c8  = (tid & 15) * 8;   // channel base
  const int swz = (rr & 7) << 4;

  const int g0 = blockIdx.x * NPB;
  const int b  = g0 >> 12;
  const int n0 = g0 & (NN - 1);
  const unsigned short* fb = featbf + (size_t)b * NN * CC;
  const int* e0 = eidx + ((b * NN + n0) * KK + rr);   // edge_index[0] (x_j)
  const int* e1 = e0 + BNK;                           // edge_index[1] (x_i)

  auto stage = [&](char* hb, uint4 Fi, uint4 Fj) {
    *(uint4*)(hb + (((rr * 256 + c8) * 2) ^ swz)) = Fi;
    uint4 d;
    unsigned int* pi = (unsigned int*)&Fi;
    unsigned int* pj = (unsigned int*)&Fj;
    unsigned int* pd = (unsigned int*)&d;
#pragma unroll
    for (int q = 0; q < 4; ++q) {
      float lo = bs2f((unsigned short)(pj[q] & 0xffff)) - bs2f((unsigned short)(pi[q] & 0xffff));
      float hi = bs2f((unsigned short)(pj[q] >> 16))    - bs2f((unsigned short)(pi[q] >> 16));
      pd[q] = ((unsigned int)(unsigned short)f2bs(lo)) |
              (((unsigned int)(unsigned short)f2bs(hi)) << 16);
    }
    *(uint4*)(hb + (((rr * 256 + 128 + c8) * 2) ^ swz)) = d;
  };

  uint4 fi, fj;   // in-flight gathers for pair p+1

  {
    int ij = e0[0], ii = e1[0];
    uint4 Fj = *(const uint4*)(fb + (size_t)ij * CC + c8);
    uint4 Fi = *(const uint4*)(fb + (size_t)ii * CC + c8);
    stage((char*)hsh[0], Fi, Fj);
    int ij1 = e0[32], ii1 = e1[32];
    fj = *(const uint4*)(fb + (size_t)ij1 * CC + c8);
    fi = *(const uint4*)(fb + (size_t)ii1 * CC + c8);
  }
  __syncthreads();

  const int asw = (l15 & 7) << 4;   // row' = nl*16+l15 -> (row'&7) == (l15&7)

  for (int p = 0; p < NPAIR; ++p) {
    char* hb = (char*)hsh[p & 1];
    char* hn = (char*)hsh[(p & 1) ^ 1];

    int ij2 = 0, ii2 = 0;
    if (p + 2 < NPAIR) { ij2 = e0[(p + 2) * 32]; ii2 = e1[(p + 2) * 32]; }

    f32x4 acc[2][2] = {};
#pragma unroll
    for (int nl = 0; nl < 2; ++nl) {
      const int rbase = (nl * 16 + l15) * 256;
#pragma unroll
      for (int t = 0; t < 8; ++t) {
        short8 a = *(short8*)(hb + (((rbase + t * 32 + lhi * 8) * 2) ^ asw));
        acc[nl][0] = __builtin_amdgcn_mfma_f32_16x16x32_bf16(a, bfrag[t][0], acc[nl][0], 0, 0, 0);
        acc[nl][1] = __builtin_amdgcn_mfma_f32_16x16x32_bf16(a, bfrag[t][1], acc[nl][1], 0, 0, 0);
      }
    }

    if (p + 1 < NPAIR) {
      stage(hn, fi, fj);
      if (p + 2 < NPAIR) {
        fj = *(const uint4*)(fb + (size_t)ij2 * CC + c8);
        fi = *(const uint4*)(fb + (size_t)ii2 * CC + c8);
      }
    }

    // epilogue: relu, K-reduce max/min, stats
#pragma unroll
    for (int nl = 0; nl < 2; ++nl) {
      const int g = g0 + 2 * p + nl;
#pragma unroll
      for (int ct = 0; ct < 2; ++ct) {
        float vmax = -1e30f, vmin = 1e30f, vs = 0.f, vq = 0.f;
#pragma unroll
        for (int i = 0; i < 4; ++i) {
          float v = acc[nl][ct][i] + biasv[ct];
          v = fmaxf(v, 0.f);
          vmax = fmaxf(vmax, v);
          vmin = fminf(vmin, v);
          vs += v;
          vq += v * v;
        }
        cs[ct] += vs;
        cq[ct] += vq;
        vmax = fmaxf(vmax, __shfl_xor(vmax, 16));
        vmax = fmaxf(vmax, __shfl_xor(vmax, 32));
        vmin = fminf(vmin, __shfl_xor(vmin, 16));
        vmin = fminf(vmin, __shfl_xor(vmin, 32));
        if (lane < 16) {
          int col = colbase + ct * 16 + l15;
          nmaxh[(size_t)g * COUT + col] = (unsigned short)f2bs(vmax);
          nminh[(size_t)g * COUT + col] = (unsigned short)f2bs(vmin);
        }
      }
    }
    __syncthreads();
  }

#pragma unroll
  for (int ct = 0; ct < 2; ++ct) {
    float s = cs[ct], q = cq[ct];
    s += __shfl_xor(s, 16);  s += __shfl_xor(s, 32);
    q += __shfl_xor(q, 16);  q += __shfl_xor(q, 32);
    if (lane < 16) {
      int col = colbase + ct * 16 + l15;
      atomicAdd(&gsum[col], s);
      atomicAdd(&gsq[col], q);
    }
  }
}

// K2: BN-affine finalize + monotone max/min select (bf16 in) + transposed out
__global__ void __launch_bounds__(256) k2_out(const unsigned short* __restrict__ nmaxh,
                                              const unsigned short* __restrict__ nminh,
                                              const float* __restrict__ gsum,
                                              const float* __restrict__ gsq,
                                              const float* __restrict__ gamma,
                                              const float* __restrict__ beta,
                                              float* __restrict__ out) {
  __shared__ float tile[COUT][33];
  int b = blockIdx.x >> 7;
  int n0 = (blockIdx.x & 127) << 5;
  int t = threadIdx.x;
  const float inv = 1.0f / (float)BNK;
  float mean = gsum[t] * inv;
  float var  = gsq[t] * inv - mean * mean;
  float sc = gamma[t] * rsqrtf(var + 1e-5f);
  float sh = beta[t] - mean * sc;
  const unsigned short* src = (sc >= 0.f) ? nmaxh : nminh;
#pragma unroll
  for (int rr = 0; rr < 32; ++rr) {
    size_t g = (size_t)(b * NN + n0 + rr) * COUT + t;
    tile[t][rr] = bs2f(src[g]) * sc + sh;
  }
  __syncthreads();
#pragma unroll
  for (int i = 0; i < 32; ++i) {
    int o = i * 8 + (t >> 5);
    int nl = t & 31;
    out[((size_t)(b * COUT + o) * NN) + n0 + nl] = tile[o][nl];
  }
}

extern "C" void kernel_launch(void* const* d_in, const int* in_sizes, int n_in,
                              void* d_out, int out_size, void* d_ws, size_t ws_size,
                              hipStream_t stream) {
  const float* x     = (const float*)d_in[0];
  const float* w     = (const float*)d_in[1];
  const float* bias  = (const float*)d_in[2];
  const float* gamma = (const float*)d_in[3];
  const float* beta  = (const float*)d_in[4];
  const int*   eidx  = (const int*)d_in[5];

  char* ws = (char*)d_ws;
  unsigned short* featbf = (unsigned short*)(ws);             //  4,194,304 B
  unsigned short* nmaxh  = (unsigned short*)(ws + 4194304);   //  8,388,608 B
  unsigned short* nminh  = (unsigned short*)(ws + 12582912);  //  8,388,608 B
  float* gsum   = (float*)(ws + 20971520);                    //      1,024 B
  float* gsq    = (float*)(ws + 20972544);                    //      1,024 B
  float* out = (float*)d_out;

  k0_transpose<<<256, 256, 0, stream>>>(x, featbf, gsum, gsq);
  k1_main<<<K1GRID, 512, 0, stream>>>(featbf, w, bias, eidx, nmaxh, nminh, gsum, gsq);
  k2_out<<<512, 256, 0, stream>>>(nmaxh, nminh, gsum, gsq, gamma, beta, out);
}